// Round 11
// baseline (70.687 us; speedup 1.0000x reference)
//
#include <hip/hip_runtime.h>

#define HP 1.57079632679489662f

typedef float f32x4 __attribute__((ext_vector_type(4)));
typedef short sh4 __attribute__((ext_vector_type(4)));
typedef __bf16 bf16x8 __attribute__((ext_vector_type(8)));

__device__ __forceinline__ unsigned short f2bf(float f) {
  unsigned int u = __builtin_bit_cast(unsigned int, f);
  u += 0x7fffu + ((u >> 16) & 1u);
  return (unsigned short)(u >> 16);
}

// ---------------- helpers for 4x4 complex matrix absorption (G*M) ----------------
__device__ __forceinline__ void rowswap4(float (&mr)[4][4], float (&mi)[4][4], int a, int b) {
#pragma unroll
  for (int c = 0; c < 4; c++) {
    float tr = mr[a][c]; mr[a][c] = mr[b][c]; mr[b][c] = tr;
    float ti = mi[a][c]; mi[a][c] = mi[b][c]; mi[b][c] = ti;
  }
}

__device__ __forceinline__ void absorb_rz(float (&mr)[4][4], float (&mi)[4][4], float t, int bitpos) {
  float ch = cosf(0.5f * t), sh = sinf(0.5f * t);
#pragma unroll
  for (int r = 0; r < 4; r++) {
    float ph = ((r >> bitpos) & 1) ? sh : -sh;
#pragma unroll
    for (int c = 0; c < 4; c++) {
      float ar = mr[r][c], ai = mi[r][c];
      mr[r][c] = ch * ar - ph * ai;
      mi[r][c] = ch * ai + ph * ar;
    }
  }
}

__device__ __forceinline__ void absorb_ry(float (&mr)[4][4], float (&mi)[4][4], float t, int bitpos) {
  float ch = cosf(0.5f * t), sh = sinf(0.5f * t);
#pragma unroll
  for (int r = 0; r < 4; r++) {
    if ((r >> bitpos) & 1) continue;
    int rb = r | (1 << bitpos);
#pragma unroll
    for (int c = 0; c < 4; c++) {
      float ar = mr[r][c], ai = mi[r][c];
      float br = mr[rb][c], bi = mi[rb][c];
      mr[r][c]  = ch * ar - sh * br;  mi[r][c]  = ch * ai - sh * bi;
      mr[rb][c] = sh * ar + ch * br;  mi[rb][c] = sh * ai + ch * bi;
    }
  }
}

// ws layout:
//   bf16 Ub[8][512][32] @ 4096 : chunk ks = k in [32ks,32ks+32); row m: 2r=Re,2r+1=Im
//        pair-packed: logical k = 32ks+16s+4g+i at row-byte p*16 + 8s + 2i, p=(g+(m>>1))&3

// ---------------- K1: one wave per column, shuffle-based, zero gate barriers ----------
// Lane holds 4 states: r = q*64 + lane (q=0..3). Bit-flip partner: bits 0-5 -> shfl_xor,
// bits 6-7 -> register slot swap. Same fused gate math as R10 (proven).
__global__ __launch_bounds__(64) void build_u_wave(const float* __restrict__ wt,
                                                   const float* __restrict__ coup,
                                                   void* __restrict__ wsv) {
  unsigned char* Ub = (unsigned char*)wsv + 4096;
  const int c = blockIdx.x;
  const int lane = threadIdx.x;

  __shared__ float Q1s[64];
  __shared__ float E4s[28 * 32];
  __shared__ int metas[57];

  // ---- inline prep (exact numpy f64 edge semantics; redundant across lanes) ----
  {
    double mn = 1e300, mx = -1e300;
    for (int k = 0; k < 64; k++) {
      double v = (double)coup[k];
      mn = v < mn ? v : mn;
      mx = v > mx ? v : mx;
    }
    int cnt = 0, myi = -1, myj = -1;
    for (int i = 0; i < 8; i++)
      for (int j = i + 1; j < 8; j++) {
        double cn = ((double)coup[i * 8 + j] - mn) / (mx - mn);
        if (cn > 0.5) {
          if (cnt == lane) { myi = i; myj = j; }
          cnt++;
        }
      }
    if (lane == 0) metas[0] = cnt;

    if (lane < 8) {
      float tx = wt[lane], ty = wt[8 + lane], tz = wt[16 + lane];
      float cx = cosf(0.5f * tx), sx = sinf(0.5f * tx);
      float cy = cosf(0.5f * ty), sy = sinf(0.5f * ty);
      float cz = cosf(0.5f * tz), sz = sinf(0.5f * tz);
      float m00r = cy * cx,  m00i = sy * sx;
      float m01r = -sy * cx, m01i = -cy * sx;
      float m10r = sy * cx,  m10i = -cy * sx;
      float m11r = cy * cx,  m11i = -sy * sx;
      float* q = Q1s + lane * 8;
      q[0] = cz * m00r + sz * m00i; q[1] = cz * m00i - sz * m00r;
      q[2] = cz * m01r + sz * m01i; q[3] = cz * m01i - sz * m01r;
      q[4] = cz * m10r - sz * m10i; q[5] = cz * m10i + sz * m10r;
      q[6] = cz * m11r - sz * m11i; q[7] = cz * m11i + sz * m11r;
    }

    if (lane < cnt && lane < 28) {
      float mr[4][4], mi[4][4];
#pragma unroll
      for (int r = 0; r < 4; r++)
#pragma unroll
        for (int cc = 0; cc < 4; cc++) { mr[r][cc] = (r == cc) ? 1.f : 0.f; mi[r][cc] = 0.f; }

      bool nonadj = (myj - myi) != 1;
      int wb = 24 + 6 * lane;

      if (nonadj) rowswap4(mr, mi, 1, 2);
      absorb_rz(mr, mi, -HP, 0);
      rowswap4(mr, mi, 1, 3);
      absorb_rz(mr, mi, wt[wb + 0], 1);
      absorb_ry(mr, mi, wt[wb + 1], 0);
      rowswap4(mr, mi, 2, 3);
      absorb_ry(mr, mi, wt[wb + 2], 0);
      rowswap4(mr, mi, 1, 3);
      absorb_rz(mr, mi, HP, 1);
      absorb_rz(mr, mi, -HP, 0);
      rowswap4(mr, mi, 1, 3);
      absorb_rz(mr, mi, wt[wb + 3], 1);
      absorb_ry(mr, mi, wt[wb + 4], 0);
      rowswap4(mr, mi, 2, 3);
      absorb_ry(mr, mi, wt[wb + 5], 0);
      if (nonadj) rowswap4(mr, mi, 1, 2);

      float* e = E4s + lane * 32;
#pragma unroll
      for (int r = 0; r < 4; r++)
#pragma unroll
        for (int cc = 0; cc < 4; cc++) {
          e[(r * 4 + cc) * 2]     = mr[r][cc];
          e[(r * 4 + cc) * 2 + 1] = mi[r][cc];
        }
      metas[1 + 2 * lane] = myi;
      metas[2 + 2 * lane] = myj;
    }
  }
  __syncthreads();

  float2 st[4];
#pragma unroll
  for (int q = 0; q < 4; q++)
    st[q] = make_float2((q * 64 + lane) == c ? 1.f : 0.f, 0.f);

  // partner amplitudes for XOR mask M (wave-uniform M)
  auto partner = [&](int M, float2 (&par)[4]) {
    const int qm = M >> 6, lm = M & 63;
    float2 t0, t1, t2, t3;
    if (qm == 0)      { t0 = st[0]; t1 = st[1]; t2 = st[2]; t3 = st[3]; }
    else if (qm == 1) { t0 = st[1]; t1 = st[0]; t2 = st[3]; t3 = st[2]; }
    else if (qm == 2) { t0 = st[2]; t1 = st[3]; t2 = st[0]; t3 = st[1]; }
    else              { t0 = st[3]; t1 = st[2]; t2 = st[1]; t3 = st[0]; }
    if (lm) {
      t0.x = __shfl_xor(t0.x, lm); t0.y = __shfl_xor(t0.y, lm);
      t1.x = __shfl_xor(t1.x, lm); t1.y = __shfl_xor(t1.y, lm);
      t2.x = __shfl_xor(t2.x, lm); t2.y = __shfl_xor(t2.y, lm);
      t3.x = __shfl_xor(t3.x, lm); t3.y = __shfl_xor(t3.y, lm);
    }
    par[0] = t0; par[1] = t1; par[2] = t2; par[3] = t3;
  };

  // ---- fused 1q per wire (wire w -> bit 7-w) ----
  for (int wi = 0; wi < 8; wi++) {
    const float* M = Q1s + wi * 8;
    const int p = 7 - wi;
    float2 par[4];
    partner(1 << p, par);
    float m00r = M[0], m00i = M[1], m01r = M[2], m01i = M[3];
    float m10r = M[4], m10i = M[5], m11r = M[6], m11i = M[7];
#pragma unroll
    for (int q = 0; q < 4; q++) {
      int b = ((q * 64 + lane) >> p) & 1;
      float2 own = st[q], pr = par[q];
      float2 x0 = b ? pr : own;   // amplitude with bit=0
      float2 x1 = b ? own : pr;   // amplitude with bit=1
      float c0r = b ? m10r : m00r, c0i = b ? m10i : m00i;
      float c1r = b ? m11r : m01r, c1i = b ? m11i : m01i;
      st[q].x = c0r * x0.x - c0i * x0.y + c1r * x1.x - c1i * x1.y;
      st[q].y = c0r * x0.y + c0i * x0.x + c1r * x1.y + c1i * x1.x;
    }
  }

  // ---- IsingXX on all pairs: new = cos*own + (-i sin)*flip_both ----
  for (int i = 0; i < 8; i++)
    for (int j = i + 1; j < 8; j++) {
      float t = coup[i * 8 + j];
      float ch = cosf(0.5f * t), sn = sinf(0.5f * t);
      int mask = (1 << (7 - i)) | (1 << (7 - j));
      float2 par[4];
      partner(mask, par);
#pragma unroll
      for (int q = 0; q < 4; q++) {
        float2 own = st[q], pr = par[q];
        st[q] = make_float2(ch * own.x + sn * pr.y, ch * own.y - sn * pr.x);
      }
    }

  // ---- fused edges ----
  int ne = metas[0];
  for (int e = 0; e < ne; e++) {
    int i = metas[1 + 2 * e], j = metas[2 + 2 * e];
    int p1 = 7 - i, p2 = 7 - j;
    int m1 = 1 << p1, m2 = 1 << p2;
    float2 pa2[4], pa1[4], pa12[4];
    partner(m2, pa2);
    partner(m1, pa1);
    partner(m1 | m2, pa12);
    const float* E = E4s + e * 32;
#pragma unroll
    for (int q = 0; q < 4; q++) {
      int r = q * 64 + lane;
      int b = ((r >> p1) & 1) * 2 + ((r >> p2) & 1);
      float nr = 0.f, ni = 0.f;
      // diff 0 (own)
      { float Mr = E[(b * 4 + b) * 2], Mi = E[(b * 4 + b) * 2 + 1];
        nr += Mr * st[q].x - Mi * st[q].y; ni += Mr * st[q].y + Mi * st[q].x; }
      // diff 1 (flip j -> pa2)
      { int t2 = b ^ 1; float Mr = E[(b * 4 + t2) * 2], Mi = E[(b * 4 + t2) * 2 + 1];
        nr += Mr * pa2[q].x - Mi * pa2[q].y; ni += Mr * pa2[q].y + Mi * pa2[q].x; }
      // diff 2 (flip i -> pa1)
      { int t2 = b ^ 2; float Mr = E[(b * 4 + t2) * 2], Mi = E[(b * 4 + t2) * 2 + 1];
        nr += Mr * pa1[q].x - Mi * pa1[q].y; ni += Mr * pa1[q].y + Mi * pa1[q].x; }
      // diff 3 (flip both -> pa12)
      { int t2 = b ^ 3; float Mr = E[(b * 4 + t2) * 2], Mi = E[(b * 4 + t2) * 2 + 1];
        nr += Mr * pa12[q].x - Mi * pa12[q].y; ni += Mr * pa12[q].y + Mi * pa12[q].x; }
      st[q] = make_float2(nr, ni);
    }
  }

  // ---- write column c into the pair-packed, slot-rotated chunk image (proven) ----
  {
    int ks = c >> 5, kc = c & 31;
    int sb = (kc >> 4) & 1, lg2 = (kc >> 2) & 3, ii = kc & 3;
#pragma unroll
    for (int q = 0; q < 4; q++) {
      int r = q * 64 + lane;
      int p = (lg2 + r) & 3;
      unsigned char* base = Ub + (size_t)ks * 32768 + (size_t)(2 * r) * 64 + p * 16 + sb * 8 + ii * 2;
      *(unsigned short*)(base)      = f2bf(st[q].x);
      *(unsigned short*)(base + 64) = f2bf(st[q].y);
    }
  }
}

// ---------------- K2: A from L2 into regs, zero K-loop barriers, chunk rotation -------
#define MFMA_STEP(KS, AREG)                                                              \
  {                                                                                      \
    uint4 bq[4];                                                                         \
    _Pragma("unroll")                                                                    \
    for (int nf = 0; nf < 4; nf++) {                                                     \
      const int n = nf * 16 + lm;                                                        \
      int byte = (n * 512 + (KS) * 64 + lg * 16) ^ ((n & 7) << 4);                       \
      bq[nf] = *reinterpret_cast<const uint4*>(&smem[byte]);                             \
    }                                                                                    \
    __builtin_amdgcn_s_setprio(1);                                                       \
    _Pragma("unroll")                                                                    \
    for (int mf = 0; mf < 4; mf++) {                                                     \
      const sh4 alo = __builtin_bit_cast(sh4, make_uint2(AREG[mf].x, AREG[mf].y));       \
      const sh4 ahi = __builtin_bit_cast(sh4, make_uint2(AREG[mf].z, AREG[mf].w));       \
      _Pragma("unroll")                                                                  \
      for (int nf = 0; nf < 4; nf++) {                                                   \
        const sh4 blo = __builtin_bit_cast(sh4, make_uint2(bq[nf].x, bq[nf].y));         \
        const sh4 bhi = __builtin_bit_cast(sh4, make_uint2(bq[nf].z, bq[nf].w));         \
        acc[mf][nf] = __builtin_amdgcn_mfma_f32_16x16x16bf16_1k(alo, blo, acc[mf][nf], 0, 0, 0); \
        acc[mf][nf] = __builtin_amdgcn_mfma_f32_16x16x16bf16_1k(ahi, bhi, acc[mf][nf], 0, 0, 0); \
      }                                                                                  \
    }                                                                                    \
    __builtin_amdgcn_s_setprio(0);                                                       \
  }

__global__ __launch_bounds__(512, 4) void gemm_l2(const float* __restrict__ x,
                                                  const void* __restrict__ wsv,
                                                  float* __restrict__ out) {
  const unsigned char* Ub = (const unsigned char*)wsv + 4096;
  __shared__ __align__(16) unsigned char smem[32768];

  const int tid = threadIdx.x;
  const int tile = blockIdx.x;
  const int wv = tid >> 6;
  const int lane = tid & 63;
  const int lm = lane & 15;
  const int lg = lane >> 4;
  const int rot = (blockIdx.x >> 3) & 7;  // same-XCD neighbors get different chunks

  // ---- hoisted: A-fragment bases + first-chunk A loads ----
  const unsigned char* abase[4];
#pragma unroll
  for (int mf = 0; mf < 4; mf++) {
    const int m = wv * 64 + mf * 16 + lm;
    const int p = (lg + (m >> 1)) & 3;
    abase[mf] = Ub + (size_t)m * 64 + p * 16;
  }
  uint4 aP[4], aQ[4];
#pragma unroll
  for (int mf = 0; mf < 4; mf++)
    aP[mf] = *reinterpret_cast<const uint4*>(abase[mf] + (size_t)rot * 32768);

  // ---- stage psi: 64 rows, normalize, pair-packed bf16 into LDS ----
  {
    const int rl = tid >> 3;
    const int seg = tid & 7;
    const float4* xs = (const float4*)(x + (size_t)(tile * 64 + rl) * 256 + seg * 32);
    float4 v[8];
    float ss = 0.f;
#pragma unroll
    for (int i = 0; i < 8; i++) {
      v[i] = xs[i];
      ss += v[i].x * v[i].x + v[i].y * v[i].y + v[i].z * v[i].z + v[i].w * v[i].w;
    }
    ss += __shfl_xor(ss, 1);
    ss += __shfl_xor(ss, 2);
    ss += __shfl_xor(ss, 4);
    float inv = 1.0f / sqrtf(ss);
    const float* vf = (const float*)v;
#pragma unroll
    for (int u = 0; u < 4; u++) {
      bf16x8 w;
#pragma unroll
      for (int j = 0; j < 8; j++)
        w[j] = (__bf16)(vf[16 * (j >> 2) + 4 * u + (j & 3)] * inv);
      uint4 pack = __builtin_bit_cast(uint4, w);
      int byte = (rl * 512 + seg * 64 + u * 16) ^ ((rl & 7) << 4);
      *reinterpret_cast<uint4*>(&smem[byte]) = pack;
    }
  }

  f32x4 acc[4][4] = {};
  __syncthreads();  // psi staged

  // ---- K loop: 8 chunks in rotated order, A double-buffered from L2, no barriers ----
#pragma unroll
  for (int kk = 0; kk < 4; kk++) {
    const int c0 = (2 * kk + rot) & 7;
    const int c1 = (2 * kk + 1 + rot) & 7;
#pragma unroll
    for (int mf = 0; mf < 4; mf++)
      aQ[mf] = *reinterpret_cast<const uint4*>(abase[mf] + (size_t)c1 * 32768);
    MFMA_STEP(c0, aP);
    if (kk < 3) {
      const int c2 = (2 * kk + 2 + rot) & 7;
#pragma unroll
      for (int mf = 0; mf < 4; mf++)
        aP[mf] = *reinterpret_cast<const uint4*>(abase[mf] + (size_t)c2 * 32768);
    }
    MFMA_STEP(c1, aQ);
  }
  __syncthreads();  // psi reads done (epilogue reuses smem)

  // ---- epilogue: prob + signed Z-reduce (validated R5-R10) ----
  float pq[4][8];
#pragma unroll
  for (int nf = 0; nf < 4; nf++) {
    float T = 0.f, S7 = 0.f, S4 = 0.f, S3 = 0.f;
#pragma unroll
    for (int mf = 0; mf < 4; mf++) {
      f32x4 a = acc[mf][nf];
      float p0 = a[0] * a[0] + a[1] * a[1];
      float p1 = a[2] * a[2] + a[3] * a[3];
      float sp = p0 + p1, d = p0 - p1;
      T += sp;
      S7 += d;
      S4 += (mf & 1) ? -sp : sp;
      S3 += (mf & 2) ? -sp : sp;
    }
    pq[nf][7] = S7;
    pq[nf][6] = (lg & 1) ? -T : T;
    pq[nf][5] = (lg & 2) ? -T : T;
    pq[nf][4] = S4;
    pq[nf][3] = S3;
    pq[nf][2] = (wv & 1) ? -T : T;
    pq[nf][1] = (wv & 2) ? -T : T;
    pq[nf][0] = (wv & 4) ? -T : T;
  }
#pragma unroll
  for (int nf = 0; nf < 4; nf++)
#pragma unroll
    for (int k = 0; k < 8; k++) {
      pq[nf][k] += __shfl_xor(pq[nf][k], 16);
      pq[nf][k] += __shfl_xor(pq[nf][k], 32);
    }

  float* part = (float*)smem;  // [8][64][8] = 16 KB
  if (lg == 0) {
#pragma unroll
    for (int nf = 0; nf < 4; nf++) {
      float* dst = part + (wv * 64 + nf * 16 + lm) * 8;
#pragma unroll
      for (int k = 0; k < 8; k++) dst[k] = pq[nf][k];
    }
  }
  __syncthreads();
  {
    int b = tid >> 3, q = tid & 7;
    float v2 = 0.f;
#pragma unroll
    for (int w2 = 0; w2 < 8; w2++) v2 += part[(w2 * 64 + b) * 8 + q];
    out[(size_t)(tile * 64 + b) * 8 + q] = v2;
  }
}

extern "C" void kernel_launch(void* const* d_in, const int* in_sizes, int n_in,
                              void* d_out, int out_size, void* d_ws, size_t ws_size,
                              hipStream_t stream) {
  const float* x    = (const float*)d_in[0];
  const float* wt   = (const float*)d_in[1];
  const float* coup = (const float*)d_in[2];
  float* out = (float*)d_out;

  build_u_wave<<<256, 64, 0, stream>>>(wt, coup, d_ws);
  gemm_l2<<<1024, 512, 0, stream>>>(x, d_ws, out);
}